// Round 9
// baseline (280.017 us; speedup 1.0000x reference)
//
#include <hip/hip_runtime.h>
#include <stdint.h>

// Problem constants
#define BB 4
#define TT 1024
#define DIM 2048
#define NH 16
#define HD 128
#define MR 4096   // BB*TT rows
#define QKVS (3 * DIM)   // 6144: row stride of fused qkv buffer

typedef __attribute__((ext_vector_type(4))) float    f32x4;
typedef __attribute__((ext_vector_type(8))) uint16_t u16x8;
typedef __attribute__((ext_vector_type(4))) uint16_t u16x4;
typedef __attribute__((ext_vector_type(4))) short    s16x4;
typedef __attribute__((ext_vector_type(8))) __bf16   bf16x8;

static __device__ __forceinline__ uint16_t f2bf(float f) {
  uint32_t u = __builtin_bit_cast(uint32_t, f);
  u += 0x7fffu + ((u >> 16) & 1u);   // round-to-nearest-even
  return (uint16_t)(u >> 16);
}
static __device__ __forceinline__ float bf2f(uint16_t b) {
  uint32_t u = ((uint32_t)b) << 16;
  return __builtin_bit_cast(float, u);
}

static __device__ __forceinline__ f32x4 mfma16(u16x8 a, u16x8 b, f32x4 c) {
  return __builtin_amdgcn_mfma_f32_16x16x32_bf16(
      __builtin_bit_cast(bf16x8, a), __builtin_bit_cast(bf16x8, b), c, 0, 0, 0);
}

// async global->LDS, 16B per lane; LDS dest = wave-uniform base + lane*16
static __device__ __forceinline__ void load_lds_16B(const void* g, void* l) {
  __builtin_amdgcn_global_load_lds(
      (const __attribute__((address_space(1))) void*)g,
      (__attribute__((address_space(3))) void*)l, 16, 0, 0);
}

// paired hardware transpose reads at byteoff and byteoff+128.
static __device__ __forceinline__ void trpair(const uint16_t* base, int byteoff,
                                              u16x4& lo, u16x4& hi) {
  __attribute__((address_space(3))) char* ap =
      (__attribute__((address_space(3))) char*)(void*)base + byteoff;
#if defined(__has_builtin) && __has_builtin(__builtin_amdgcn_ds_read_tr16_b64_v4i16)
  s16x4 r0 = __builtin_amdgcn_ds_read_tr16_b64_v4i16(
      (__attribute__((address_space(3))) s16x4*)ap);
  s16x4 r1 = __builtin_amdgcn_ds_read_tr16_b64_v4i16(
      (__attribute__((address_space(3))) s16x4*)(ap + 128));
  lo = __builtin_bit_cast(u16x4, r0);
  hi = __builtin_bit_cast(u16x4, r1);
#else
  uint32_t a32 = (uint32_t)(uintptr_t)ap;
  asm volatile("ds_read_b64_tr_b16 %0, %2\n\t"
               "ds_read_b64_tr_b16 %1, %2 offset:128\n\t"
               "s_waitcnt lgkmcnt(0)"
               : "=&v"(lo), "=&v"(hi) : "v"(a32));
#endif
}

// ---------------- casts fp32 -> bf16 (vectorized) ----------------
__global__ __launch_bounds__(256) void cast_f32_bf16(const float* __restrict__ in,
                                                     uint16_t* __restrict__ out, int n4) {
  int i = blockIdx.x * 256 + threadIdx.x;
  if (i >= n4) return;
  f32x4 v = ((const f32x4*)in)[i];
  u16x4 o;
  o[0] = f2bf(v[0]); o[1] = f2bf(v[1]); o[2] = f2bf(v[2]); o[3] = f2bf(v[3]);
  ((u16x4*)out)[i] = o;
}

// three equal-size sources -> one contiguous dest (wq|wk|wv)
__global__ __launch_bounds__(256) void cast3_f32_bf16(const float* __restrict__ s0,
                                                      const float* __restrict__ s1,
                                                      const float* __restrict__ s2,
                                                      uint16_t* __restrict__ out) {
  const int per = 4194304 / 4;   // f32x4 chunks per matrix
  int i = blockIdx.x * 256 + threadIdx.x;          // [0, 3*per)
  const float* src = (i < per) ? s0 : (i < 2 * per) ? s1 : s2;
  int j = (i < per) ? i : (i < 2 * per) ? (i - per) : (i - 2 * per);
  f32x4 v = ((const f32x4*)src)[j];
  u16x4 o;
  o[0] = f2bf(v[0]); o[1] = f2bf(v[1]); o[2] = f2bf(v[2]); o[3] = f2bf(v[3]);
  ((u16x4*)out)[i] = o;
}

// ---------------- GEMM 256x256, BK=32, 4-slot + reg-prefetch ----------------
// C[M,N] = A[M,K] * Bt[N,K]^T (bf16 row-major). 512 thr = 8 waves (2M x 4N);
// per-wave C = 128x64 = 8x4 16x16 frags. LDS: 4 slots x 32 KiB = 128 KiB.
// Pipeline per iter t: vmcnt(4) [tile t+1 landed, t+2 in flight] -> barrier ->
// stage(t+3) -> ds_read frags(t+1) into NEXT reg set -> 32 MFMA on CURRENT
// set (reads overlap MFMA: no dependency) -> swap sets. Swizzle ch^((row>>1)&3)
// on 16B chunks; swizzle chunk is m-invariant -> one LDS base + offsets.
// MODE: 1 = f32 out, 2 = bf16 out + fused RoPE on cols [0, 2*DIM).
template <int MODE>
__global__ __launch_bounds__(512, 1) void gemm256q(const uint16_t* __restrict__ A,
                                                   const uint16_t* __restrict__ Bt,
                                                   float* __restrict__ Cf,
                                                   uint16_t* __restrict__ Cb,
                                                   const float* __restrict__ cosT,
                                                   const float* __restrict__ sinT,
                                                   int M, int N, int K) {
  extern __shared__ __attribute__((aligned(16))) uint16_t smem[];  // 131072 B
  const int tid  = threadIdx.x;
  const int lane = tid & 63;
  const int wave = tid >> 6;          // 0..7
  const int lrow = lane & 15;
  const int lgrp = lane >> 4;
  const int wr   = (wave >> 2) * 128; // 0 / 128
  const int wc   = (wave & 3) * 64;   // 0,64,128,192

  // T1: XCD-aware block swizzle (grid % 8 == 0)
  const int nbx = N >> 8, nby = M >> 8;
  const int nwg = nbx * nby;
  const int wg  = ((int)blockIdx.x & 7) * (nwg >> 3) + ((int)blockIdx.x >> 3);
  const long bRow = (long)(wg / nbx) << 8;
  const long bCol = (long)(wg % nbx) << 8;

  const f32x4 fz = {0.f, 0.f, 0.f, 0.f};
  f32x4 acc[8][4];
#pragma unroll
  for (int m = 0; m < 8; ++m)
#pragma unroll
    for (int n = 0; n < 4; ++n) acc[m][n] = fz;

  auto stage = [&](int kt, int slot) {
    const long kb = (long)kt << 5;
    char* Abase = (char*)smem + slot * 32768;
    char* Bbase = Abase + 16384;
#pragma unroll
    for (int i = 0; i < 2; ++i) {
      const int L   = (i * 512 + tid) * 16;
      const int row = L >> 6;                           // 0..255
      const int c   = ((L >> 4) & 3) ^ ((row >> 1) & 3);
      load_lds_16B(A + (bRow + row) * (long)K + kb + c * 8, Abase + L);
    }
#pragma unroll
    for (int i = 0; i < 2; ++i) {
      const int L   = (i * 512 + tid) * 16;
      const int row = L >> 6;
      const int c   = ((L >> 4) & 3) ^ ((row >> 1) & 3);
      load_lds_16B(Bt + (bCol + row) * (long)K + kb + c * 8, Bbase + L);
    }
  };

  const int NT = K >> 5;   // 64 K-tiles

  // frag read: tile t's 8 A + 4 B fragments (swizzle chunk m-invariant)
#define READF(T, FA, FB)                                                      \
  {                                                                           \
    const char* Ab_ = (const char*)smem + ((T) & 3) * 32768;                  \
    const char* Bb_ = Ab_ + 16384;                                            \
    _Pragma("unroll")                                                         \
    for (int m = 0; m < 8; ++m) {                                             \
      const int row = wr + m * 16 + lrow;                                     \
      FA[m] = *(const u16x8*)(Ab_ + row * 64 + (lgrp ^ ((row >> 1) & 3)) * 16);\
    }                                                                         \
    _Pragma("unroll")                                                         \
    for (int n = 0; n < 4; ++n) {                                             \
      const int row = wc + n * 16 + lrow;                                     \
      FB[n] = *(const u16x8*)(Bb_ + row * 64 + (lgrp ^ ((row >> 1) & 3)) * 16);\
    }                                                                         \
  }

#define ITER(T, CA, CB, NA, NB)                                               \
  {                                                                           \
    if ((T) + 1 < NT) {                                                       \
      if ((T) + 2 < NT) asm volatile("s_waitcnt vmcnt(4)" ::: "memory");      \
      else              asm volatile("s_waitcnt vmcnt(0)" ::: "memory");      \
      __builtin_amdgcn_s_barrier();                                           \
      if ((T) + 3 < NT) stage((T) + 3, ((T) + 3) & 3);                        \
      READF((T) + 1, NA, NB)                                                  \
    }                                                                         \
    __builtin_amdgcn_s_setprio(1);                                            \
    _Pragma("unroll")                                                         \
    for (int m = 0; m < 8; ++m)                                               \
      _Pragma("unroll")                                                       \
      for (int n = 0; n < 4; ++n) acc[m][n] = mfma16(CA[m], CB[n], acc[m][n]);\
    __builtin_amdgcn_s_setprio(0);                                            \
  }

  stage(0, 0); stage(1, 1); stage(2, 2);   // 12 loads in flight
  asm volatile("s_waitcnt vmcnt(8)" ::: "memory");  // tile 0 landed
  __builtin_amdgcn_s_barrier();

  u16x8 fa0[8], fb0[4], fa1[8], fb1[4];
  READF(0, fa0, fb0)

  for (int t = 0; t < NT; t += 2) {
    ITER(t, fa0, fb0, fa1, fb1)
    ITER(t + 1, fa1, fb1, fa0, fb0)
  }
#undef ITER
#undef READF

  // epilogue (MODE 2: fused RoPE on q/k column range)
  const bool doRope = (MODE == 2) && (bCol < 2 * DIM);
#pragma unroll
  for (int m = 0; m < 8; ++m)
#pragma unroll
    for (int n = 0; n < 4; ++n) {
      const long grow0 = bRow + wr + m * 16 + lgrp * 4;
      const long gcol  = bCol + wc + n * 16 + lrow;
      if (doRope) {
        const int  fi  = ((int)gcol >> 1) & 63;
        const bool odd = (gcol & 1) != 0;
#pragma unroll
        for (int r = 0; r < 4; ++r) {
          const long grow = grow0 + r;
          const int  ttt  = (int)grow & (TT - 1);
          float v = acc[m][n][r];
          float p = __shfl_xor(v, 1, 64);   // partner column (lane^1)
          float cc = cosT[ttt * 64 + fi];
          float ss = sinT[ttt * 64 + fi];
          float o  = odd ? (p * ss + v * cc) : (v * cc - p * ss);
          Cb[grow * (long)N + gcol] = f2bf(o);
        }
      } else {
#pragma unroll
        for (int r = 0; r < 4; ++r) {
          const long idx = (grow0 + r) * (long)N + gcol;
          if (MODE == 1) Cf[idx] = acc[m][n][r];
          else           Cb[idx] = f2bf(acc[m][n][r]);
        }
      }
    }
}

// ---------------- GEMM 128x128, BK=32, 4-slot + reg-prefetch (out-proj) ------
template <int MODE>   // 1 = f32 out
__global__ __launch_bounds__(256, 2) void gemm128(const uint16_t* __restrict__ A,
                                                  const uint16_t* __restrict__ Bt,
                                                  float* __restrict__ Cf,
                                                  uint16_t* __restrict__ Cb,
                                                  int M, int N, int K) {
  extern __shared__ __attribute__((aligned(16))) uint16_t smem[];  // 65536 B
  const int tid  = threadIdx.x;
  const int lane = tid & 63;
  const int wave = tid >> 6;
  const int lrow = lane & 15;
  const int lgrp = lane >> 4;
  const int wr   = (wave >> 1) * 64;
  const int wc   = (wave & 1) * 64;

  const int nbx = N >> 7, nby = M >> 7;
  const int nwg = nbx * nby;
  const int wg  = ((int)blockIdx.x & 7) * (nwg >> 3) + ((int)blockIdx.x >> 3);
  const long bRow = (long)(wg / nbx) << 7;
  const long bCol = (long)(wg % nbx) << 7;

  const f32x4 fz = {0.f, 0.f, 0.f, 0.f};
  f32x4 acc[4][4];
#pragma unroll
  for (int m = 0; m < 4; ++m)
#pragma unroll
    for (int n = 0; n < 4; ++n) acc[m][n] = fz;

  auto stage = [&](int kt, int buf) {
    const long kb = (long)kt << 5;
    char* base = (char*)smem + buf * 16384;
#pragma unroll
    for (int i = 0; i < 2; ++i) {
      const int L   = (i * 256 + tid) * 16;
      const int row = L >> 6;
      const int c   = ((L >> 4) & 3) ^ ((row >> 1) & 3);
      load_lds_16B(A + (bRow + row) * (long)K + kb + c * 8, base + L);
    }
#pragma unroll
    for (int i = 0; i < 2; ++i) {
      const int L   = (i * 256 + tid) * 16;
      const int row = L >> 6;
      const int c   = ((L >> 4) & 3) ^ ((row >> 1) & 3);
      load_lds_16B(Bt + (bCol + row) * (long)K + kb + c * 8, base + 8192 + L);
    }
  };

  const int NT = K >> 5;

#define READF(T, FA, FB)                                                      \
  {                                                                           \
    const char* Ab_ = (const char*)smem + ((T) & 3) * 16384;                  \
    const char* Bb_ = Ab_ + 8192;                                             \
    _Pragma("unroll")                                                         \
    for (int m = 0; m < 4; ++m) {                                             \
      const int row = wr + m * 16 + lrow;                                     \
      FA[m] = *(const u16x8*)(Ab_ + row * 64 + (lgrp ^ ((row >> 1) & 3)) * 16);\
    }                                                                         \
    _Pragma("unroll")                                                         \
    for (int n = 0; n < 4; ++n) {                                             \
      const int row = wc + n * 16 + lrow;                                     \
      FB[n] = *(const u16x8*)(Bb_ + row * 64 + (lgrp ^ ((row >> 1) & 3)) * 16);\
    }                                                                         \
  }

#define ITER(T, CA, CB, NA, NB)                                               \
  {                                                                           \
    if ((T) + 1 < NT) {                                                       \
      if ((T) + 2 < NT) asm volatile("s_waitcnt vmcnt(4)" ::: "memory");      \
      else              asm volatile("s_waitcnt vmcnt(0)" ::: "memory");      \
      __builtin_amdgcn_s_barrier();                                           \
      if ((T) + 3 < NT) stage((T) + 3, ((T) + 3) & 3);                        \
      READF((T) + 1, NA, NB)                                                  \
    }                                                                         \
    __builtin_amdgcn_s_setprio(1);                                            \
    _Pragma("unroll")                                                         \
    for (int m = 0; m < 4; ++m)                                               \
      _Pragma("unroll")                                                       \
      for (int n = 0; n < 4; ++n) acc[m][n] = mfma16(CA[m], CB[n], acc[m][n]);\
    __builtin_amdgcn_s_setprio(0);                                            \
  }

  stage(0, 0); stage(1, 1); stage(2, 2);
  asm volatile("s_waitcnt vmcnt(8)" ::: "memory");
  __builtin_amdgcn_s_barrier();

  u16x8 fa0[4], fb0[4], fa1[4], fb1[4];
  READF(0, fa0, fb0)

  for (int t = 0; t < NT; t += 2) {
    ITER(t, fa0, fb0, fa1, fb1)
    ITER(t + 1, fa1, fb1, fa0, fb0)
  }
#undef ITER
#undef READF

#pragma unroll
  for (int m = 0; m < 4; ++m)
#pragma unroll
    for (int n = 0; n < 4; ++n) {
      const long grow0 = bRow + wr + m * 16 + lgrp * 4;
      const long gcol  = bCol + wc + n * 16 + lrow;
#pragma unroll
      for (int r = 0; r < 4; ++r) {
        const long idx = (grow0 + r) * (long)N + gcol;
        if (MODE == 1) Cf[idx] = acc[m][n][r];
        else           Cb[idx] = f2bf(acc[m][n][r]);
      }
    }
}

// ---------------- Flash attention fwd ---------------------------------------
__global__ __launch_bounds__(256) void attn_fwd(const uint16_t* __restrict__ Q,
                                                const uint16_t* __restrict__ K,
                                                const uint16_t* __restrict__ V,
                                                uint16_t* __restrict__ O) {
  __shared__ __attribute__((aligned(16))) uint16_t Ks[2][64 * 128];
  __shared__ __attribute__((aligned(16))) uint16_t Vs[2][64 * 128];
  __shared__ __attribute__((aligned(16))) uint16_t Ps[4][16][72];
  const int tid  = threadIdx.x;
  const int lane = tid & 63;
  const int wave = tid >> 6;
  const int lrow = lane & 15;
  const int lgrp = lane >> 4;
  const int b  = blockIdx.x >> 4;
  const int h  = blockIdx.x & 15;
  const int qt = blockIdx.y;
  const long colBase = (long)h * HD;
  const long rs = QKVS;
  const long os = DIM;
  const long qrow0 = (long)b * TT + qt * 64 + wave * 16;

  u16x8 qf[4];
#pragma unroll
  for (int kkk = 0; kkk < 4; ++kkk)
    qf[kkk] = *(const u16x8*)(Q + (qrow0 + lrow) * rs + colBase + kkk * 32 + lgrp * 8);

  const f32x4 fz = {0.f, 0.f, 0.f, 0.f};
  f32x4 oacc[8];
#pragma unroll
  for (int nf = 0; nf < 8; ++nf) oacc[nf] = fz;
  float mst[4] = {-1e30f, -1e30f, -1e30f, -1e30f};
  float lst[4] = {0.f, 0.f, 0.f, 0.f};
  const float scale = 0.08838834764831845f;

  auto stage = [&](int kt, int buf) {
    const long krow = (long)b * TT + kt * 64;
#pragma unroll
    for (int i = 0; i < 4; ++i) {
      const int L = (i * 256 + tid) * 16;
      const int krw = L >> 8;
      const int ksc = ((L >> 4) & 15) ^ (krw & 7);
      load_lds_16B(K + (krow + krw) * rs + colBase + ksc * 8,
                   (char*)&Ks[buf][0] + L);
      const int vbl = L >> 11;
      const int vkv = ((L >> 7) & 15) * 4 + ((L >> 5) & 3);
      const int vd  = vbl * 16 + ((L >> 4) & 1) * 8;
      load_lds_16B(V + (krow + vkv) * rs + colBase + vd,
                   (char*)&Vs[buf][0] + L);
    }
  };

  stage(0, 0);

  for (int kt2 = 0; kt2 < TT / 64; ++kt2) {
    const int cur = kt2 & 1;
    if (kt2 < TT / 64 - 1) {
      stage(kt2 + 1, cur ^ 1);
      asm volatile("s_waitcnt vmcnt(8)" ::: "memory");
    } else {
      asm volatile("s_waitcnt vmcnt(0)" ::: "memory");
    }
    __builtin_amdgcn_s_barrier();

    f32x4 sacc[4];
#pragma unroll
    for (int n = 0; n < 4; ++n) sacc[n] = fz;
    __builtin_amdgcn_s_setprio(1);
#pragma unroll
    for (int kkk = 0; kkk < 4; ++kkk) {
#pragma unroll
      for (int n = 0; n < 4; ++n) {
        const int row = n * 16 + lrow;
        const int ch  = (kkk * 4 + lgrp) ^ (row & 7);
        u16x8 bfr = *(const u16x8*)((const char*)&Ks[cur][0] + row * 256 + ch * 16);
        sacc[n] = mfma16(qf[kkk], bfr, sacc[n]);
      }
    }
    __builtin_amdgcn_s_setprio(0);
#pragma unroll
    for (int n = 0; n < 4; ++n) sacc[n] *= scale;

    float rmax[4];
#pragma unroll
    for (int r = 0; r < 4; ++r)
      rmax[r] = fmaxf(fmaxf(sacc[0][r], sacc[1][r]), fmaxf(sacc[2][r], sacc[3][r]));
#pragma unroll
    for (int off = 8; off >= 1; off >>= 1)
#pragma unroll
      for (int r = 0; r < 4; ++r)
        rmax[r] = fmaxf(rmax[r], __shfl_xor(rmax[r], off, 64));

    bool need = false;
#pragma unroll
    for (int r = 0; r < 4; ++r) need = need || (rmax[r] > mst[r] + 8.0f);
    if (__any(need)) {
#pragma unroll
      for (int r = 0; r < 4; ++r) {
        float mnew  = fmaxf(mst[r], rmax[r]);
        float alpha = __expf(mst[r] - mnew);
        mst[r] = mnew;
        lst[r] *= alpha;
#pragma unroll
        for (int nf = 0; nf < 8; ++nf) oacc[nf][r] *= alpha;
      }
    }

    float rsum[4] = {0.f, 0.f, 0.f, 0.f};
#pragma unroll
    for (int n = 0; n < 4; ++n)
#pragma unroll
      for (int r = 0; r < 4; ++r) {
        float pv = __expf(sacc[n][r] - mst[r]);
        rsum[r] += pv;
        Ps[wave][lgrp * 4 + r][n * 16 + lrow] = f2bf(pv);
      }
#pragma unroll
    for (int off = 8; off >= 1; off >>= 1)
#pragma unroll
      for (int r = 0; r < 4; ++r) rsum[r] += __shfl_xor(rsum[r], off, 64);
#pragma unroll
    for (int r = 0; r < 4; ++r) lst[r] += rsum[r];

    asm volatile("s_waitcnt lgkmcnt(0)" ::: "memory");

    __builtin_amdgcn_s_setprio(1);
#pragma unroll
    for (int kk2 = 0; kk2 < 2; ++kk2) {
      u16x8 af = *(const u16x8*)&Ps[wave][lrow][kk2 * 32 + lgrp * 8];
#pragma unroll
      for (int nf = 0; nf < 8; ++nf) {
        const int vbase = nf * 2048 + kk2 * 1024 + lgrp * 256 + lrow * 8;
        u16x4 lo, hi;
        trpair(&Vs[cur][0], vbase, lo, hi);
        u16x8 bfr;
        bfr[0] = lo[0]; bfr[1] = lo[1]; bfr[2] = lo[2]; bfr[3] = lo[3];
        bfr[4] = hi[0]; bfr[5] = hi[1]; bfr[6] = hi[2]; bfr[7] = hi[3];
        oacc[nf] = mfma16(af, bfr, oacc[nf]);
      }
    }
    __builtin_amdgcn_s_setprio(0);

    __builtin_amdgcn_s_barrier();
  }

  float inv[4];
#pragma unroll
  for (int r = 0; r < 4; ++r) inv[r] = 1.0f / lst[r];
#pragma unroll
  for (int nf = 0; nf < 8; ++nf)
#pragma unroll
    for (int r = 0; r < 4; ++r)
      O[(qrow0 + lgrp * 4 + r) * os + colBase + nf * 16 + lrow] =
          f2bf(oacc[nf][r] * inv[r]);
}

// ---------------- launch ----------------------------------------------------
extern "C" void kernel_launch(void* const* d_in, const int* in_sizes, int n_in,
                              void* d_out, int out_size, void* d_ws, size_t ws_size,
                              hipStream_t stream) {
  const float* x  = (const float*)d_in[0];
  const float* fc = (const float*)d_in[1];
  const float* fs = (const float*)d_in[2];
  const float* wq = (const float*)d_in[3];
  const float* wk = (const float*)d_in[4];
  const float* wv = (const float*)d_in[5];
  const float* wo = (const float*)d_in[6];
  float* out = (float*)d_out;

  uint16_t* w16  = (uint16_t*)d_ws;
  uint16_t* xb   = w16;                   //  8,388,608  x  [4096][2048]
  uint16_t* wqkv = xb + 8388608;          // 12,582,912  [6144][2048]
  uint16_t* wob  = wqkv + 12582912;       //  4,194,304  [2048][2048]
  uint16_t* qkv  = wob + 4194304;         // 25,165,824  [4096][6144]
  uint16_t* ob   = qkv + 25165824;        //  8,388,608  [4096][2048]

  static int lds_ok = [] {
    (void)hipFuncSetAttribute((const void*)gemm256q<2>,
                              hipFuncAttributeMaxDynamicSharedMemorySize, 131072);
    (void)hipFuncSetAttribute((const void*)gemm128<1>,
                              hipFuncAttributeMaxDynamicSharedMemorySize, 65536);
    return 1;
  }();
  (void)lds_ok;

  // casts
  cast_f32_bf16<<<8192, 256, 0, stream>>>(x, xb, 8388608 / 4);
  cast3_f32_bf16<<<3 * 4096, 256, 0, stream>>>(wq, wk, wv, wqkv);
  cast_f32_bf16<<<4096, 256, 0, stream>>>(wo, wob, 4194304 / 4);

  // fused QKV projection + RoPE epilogue: [4096][6144] = xb @ wqkv^T
  gemm256q<2><<<(MR / 256) * (QKVS / 256), 512, 131072, stream>>>(
      xb, wqkv, nullptr, qkv, fc, fs, MR, QKVS, DIM);

  // attention: Q,K,V strided views into qkv
  dim3 ga(BB * NH, TT / 64);
  attn_fwd<<<ga, 256, 0, stream>>>(qkv, qkv + DIM, qkv + 2 * DIM, ob);

  // output projection -> fp32 d_out
  gemm128<1><<<(MR / 128) * (DIM / 128), 256, 65536, stream>>>(
      ob, wob, out, nullptr, MR, DIM, DIM);
}